// Round 5
// baseline (79.214 us; speedup 1.0000x reference)
//
#include <hip/hip_runtime.h>

#define BOUNDING_PERC 0.05f

// ---------------------------------------------------------------------------
// scatter_inv: inv[pos[j]] = j   (inv pre-filled with -1 via hipMemsetAsync)
// ---------------------------------------------------------------------------
__global__ __launch_bounds__(256) void scatter_inv_kernel(
    const int* __restrict__ pos, int* __restrict__ inv, int nb)
{
    int j = blockIdx.x * blockDim.x + threadIdx.x;
    if (j < nb) inv[pos[j]] = j;
}

// ---------------------------------------------------------------------------
// Fused persistent kernel. Grid-stride over 256-face tiles.
//  - wave-private LDS staging (each wave writes & reads ONLY its own
//    144-float4 region) -> NO __syncthreads anywhere
//  - software pipeline: tile i+1's source/kernel prefetched into registers
//    during tile i's compute
//  - bb/f from one uniform division per tile (tile spans <= 2 batches)
// ---------------------------------------------------------------------------
__global__ __launch_bounds__(256) void fused_kernel(
    const float4* __restrict__ k4,    // (b*nfaces) float4's
    const float4* __restrict__ s4,    // (b*nfaces*9/4) float4's
    const float*  __restrict__ W,     // [4][9]
    const float*  __restrict__ bias,  // [9]
    const int*    __restrict__ inv,   // (nfaces), -1 = not in positions
    const float*  __restrict__ uc,    // (b*ncells)
    const int*    __restrict__ own,   // (nb)
    const int*    __restrict__ nei,   // (nb)
    float*        __restrict__ out,   // (b*nfaces)
    int nfaces, int ncells, int ntiles)
{
    __shared__ float4 sm[576];                 // 4 waves * 144 float4
    const int tid  = threadIdx.x;
    const int wv   = tid >> 6;
    const int lane = tid & 63;
    float4* mysm = sm + wv * 144;              // wave-private region
    const float* S = reinterpret_cast<const float*>(mysm) + lane * 9;

    // Uniform weights -> SGPRs
    float Wr[4][9];
#pragma unroll
    for (int i = 0; i < 4; ++i)
#pragma unroll
        for (int s = 0; s < 9; ++s)
            Wr[i][s] = W[i * 9 + s];
    float br[9];
#pragma unroll
    for (int s = 0; s < 9; ++s) br[s] = bias[s];

    const int stride = gridDim.x;
    int tile = blockIdx.x;
    if (tile >= ntiles) return;

    // Prologue: issue loads for first tile
    const float4* sb = s4 + (size_t)tile * 576 + wv * 144;
    float4 a0 = sb[lane];
    float4 a1 = sb[lane + 64];
    float4 a2;
    if (lane < 16) a2 = sb[lane + 128];
    float4 kv = k4[(size_t)tile * 256 + tid];

    while (true) {
        const int nt = tile + stride;
        float4 b0, b1, b2, kv2;
        if (nt < ntiles) {                     // prefetch next tile
            const float4* sb2 = s4 + (size_t)nt * 576 + wv * 144;
            b0 = sb2[lane];
            b1 = sb2[lane + 64];
            if (lane < 16) b2 = sb2[lane + 128];
            kv2 = k4[(size_t)nt * 256 + tid];
        }

        // Stage current tile into wave-private LDS
        mysm[lane]      = a0;
        mysm[lane + 64] = a1;
        if (lane < 16) mysm[lane + 128] = a2;

        const int gbase = tile << 8;
        const int g     = gbase + tid;
        const int ubb   = gbase / nfaces;      // uniform per tile
        int f  = gbase - ubb * nfaces + tid;
        int bb = ubb;
        if (f >= nfaces) { f -= nfaces; ++bb; }
        const int j = inv[f];                  // coalesced dword

        float acc = 0.0f;
#pragma unroll
        for (int s = 0; s < 9; ++s) {
            float c = br[s];
            c = fmaf(kv.x, Wr[0][s], c);
            c = fmaf(kv.y, Wr[1][s], c);
            c = fmaf(kv.z, Wr[2][s], c);
            c = fmaf(kv.w, Wr[3][s], c);
            acc = fmaf(c, S[s], acc);
        }

        float res = acc;
        if (j >= 0) {
            float o = uc[bb * ncells + own[j]];
            float n = uc[bb * ncells + nei[j]];
            float smax = fmaxf(o, n);
            float smin = fminf(o, n);
            float flux = 0.5f * (o + n);
            float up   = (flux >= 0.0f) ? o : n;
            float hi   = smax + BOUNDING_PERC * fabsf(smax);
            float lo   = smin - BOUNDING_PERC * fabsf(smin);
            bool valid = (acc >= lo) && (acc <= hi);
            res = valid ? acc : up;
        }
        out[g] = res;

        if (nt >= ntiles) break;
        a0 = b0; a1 = b1; a2 = b2; kv = kv2;
        tile = nt;
    }
}

// ---------------------------------------------------------------------------
// Fallback pass-1/pass-2 (used only if ws_size is too small for inv map)
// ---------------------------------------------------------------------------
__global__ __launch_bounds__(256) void ufaces_kernel(
    const float4* __restrict__ k4, const float4* __restrict__ s4,
    const float* __restrict__ W, const float* __restrict__ bias,
    float* __restrict__ out)
{
    __shared__ float s_src[2304];
    const int tid = threadIdx.x;
    const int base_face = blockIdx.x << 8;
    {
        const float4* src_blk = s4 + ((size_t)base_face * 9) / 4;
        float4* sm4 = reinterpret_cast<float4*>(s_src);
        sm4[tid]       = src_blk[tid];
        sm4[tid + 256] = src_blk[tid + 256];
        if (tid < 64) sm4[tid + 512] = src_blk[tid + 512];
    }
    float Wr[4][9];
#pragma unroll
    for (int i = 0; i < 4; ++i)
#pragma unroll
        for (int s = 0; s < 9; ++s) Wr[i][s] = W[i * 9 + s];
    float br[9];
#pragma unroll
    for (int s = 0; s < 9; ++s) br[s] = bias[s];
    const float4 kv = k4[base_face + tid];
    __syncthreads();
    const float* S = &s_src[tid * 9];
    float acc = 0.0f;
#pragma unroll
    for (int s = 0; s < 9; ++s) {
        float c = br[s];
        c = fmaf(kv.x, Wr[0][s], c);
        c = fmaf(kv.y, Wr[1][s], c);
        c = fmaf(kv.z, Wr[2][s], c);
        c = fmaf(kv.w, Wr[3][s], c);
        acc = fmaf(c, S[s], acc);
    }
    out[base_face + tid] = acc;
}

__global__ __launch_bounds__(256) void bound_kernel(
    const float* __restrict__ uc, const int* __restrict__ pos,
    const int* __restrict__ own, const int* __restrict__ nei,
    float* __restrict__ out, int nb, int nfaces, int ncells, int nbatch)
{
    int idx = blockIdx.x * blockDim.x + threadIdx.x;
    if (idx >= nbatch * nb) return;
    int j  = idx % nb;
    int bb = idx / nb;
    int p = pos[j];
    float uf = out[bb * nfaces + p];
    float o  = uc[bb * ncells + own[j]];
    float n  = uc[bb * ncells + nei[j]];
    float smax = fmaxf(o, n);
    float smin = fminf(o, n);
    float flux = 0.5f * (o + n);
    float up   = (flux >= 0.0f) ? o : n;
    float hi   = smax + BOUNDING_PERC * fabsf(smax);
    float lo   = smin - BOUNDING_PERC * fabsf(smin);
    bool valid = (uf >= lo) && (uf <= hi);
    out[bb * nfaces + p] = valid ? uf : up;
}

extern "C" void kernel_launch(void* const* d_in, const int* in_sizes, int n_in,
                              void* d_out, int out_size, void* d_ws, size_t ws_size,
                              hipStream_t stream)
{
    const float* kernel_in  = (const float*)d_in[0];  // (b, nfaces, 4)
    const float* source     = (const float*)d_in[1];  // (b, nfaces, 3, 3)
    const float* ucenters   = (const float*)d_in[2];  // (b, ncells)
    const float* W          = (const float*)d_in[3];  // (4, 9)
    const float* bias       = (const float*)d_in[4];  // (9,)
    const int*   positions  = (const int*)d_in[5];    // (nb,)
    const int*   owners     = (const int*)d_in[6];    // (nb,)
    const int*   neighbours = (const int*)d_in[7];    // (nb,)
    float*       out        = (float*)d_out;          // (b, nfaces)

    const int b      = 4;
    const int in_dim = 4;
    const int nfaces = in_sizes[0] / (b * in_dim);
    const int ncells = in_sizes[2] / b;
    const int nb     = in_sizes[5];
    const int total_faces = b * nfaces;               // 4,000,000 (div by 256)
    const int ntiles = total_faces / 256;

    if (ws_size >= (size_t)nfaces * sizeof(int)) {
        int* inv = (int*)d_ws;
        hipMemsetAsync(inv, 0xFF, (size_t)nfaces * sizeof(int), stream);
        scatter_inv_kernel<<<(nb + 255) / 256, 256, 0, stream>>>(positions, inv, nb);

        int grid = 2048;
        if (grid > ntiles) grid = ntiles;
        fused_kernel<<<grid, 256, 0, stream>>>(
            (const float4*)kernel_in, (const float4*)source, W, bias,
            inv, ucenters, owners, neighbours, out, nfaces, ncells, ntiles);
    } else {
        ufaces_kernel<<<total_faces / 256, 256, 0, stream>>>(
            (const float4*)kernel_in, (const float4*)source, W, bias, out);
        int total = b * nb;
        bound_kernel<<<(total + 255) / 256, 256, 0, stream>>>(
            ucenters, positions, owners, neighbours, out, nb, nfaces, ncells, b);
    }
}

// Round 6
// 61.305 us; speedup vs baseline: 1.2921x; 1.2921x over previous
//
#include <hip/hip_runtime.h>

#define BOUNDING_PERC 0.05f

// ---------------------------------------------------------------------------
// Prep: own_f[pos[j]] = owners[j]; nei_f[pos[j]] = neighbours[j]
// own_f pre-filled with -1 (hipMemsetAsync 0xFF) as "no fixup" sentinel.
// nei_f needs no init: it is read only where own_f >= 0 (i.e. written slots).
// ---------------------------------------------------------------------------
__global__ __launch_bounds__(256) void scatter_on_kernel(
    const int* __restrict__ pos, const int* __restrict__ own,
    const int* __restrict__ nei,
    int* __restrict__ own_f, int* __restrict__ nei_f, int nb)
{
    int j = blockIdx.x * blockDim.x + threadIdx.x;
    if (j < nb) {
        int p = pos[j];
        own_f[p] = own[j];
        nei_f[p] = nei[j];
    }
}

// ---------------------------------------------------------------------------
// Fused kernel, barrier-free:
//  - one thread per face, 256 faces/block, 4 independent waves
//  - wave-private LDS staging of source (576 floats/wave): each wave writes
//    and reads ONLY its own region -> NO __syncthreads anywhere
//  - front burst per lane: 2x float4 + 1x f32 (source), float4 (kernel),
//    own_f, nei_f  -- all coalesced, issued together
//  - the single remaining dependent gather (ucenters) is issued BEFORE the
//    45-FMA dot so its latency hides under compute
// ---------------------------------------------------------------------------
__global__ __launch_bounds__(256) void fused_kernel(
    const float4* __restrict__ k4,     // (b*nfaces) float4's
    const float4* __restrict__ s4,     // (b*nfaces*9/4) float4's
    const float*  __restrict__ W,      // [4][9]
    const float*  __restrict__ bias,   // [9]
    const int*    __restrict__ own_f,  // (nfaces), -1 = no fixup
    const int*    __restrict__ nei_f,  // (nfaces)
    const float*  __restrict__ uc,     // (b*ncells)
    float*        __restrict__ out,    // (b*nfaces)
    int nfaces, int ncells)
{
    __shared__ float smem[2304];               // 4 waves * 576 floats
    const int tid  = threadIdx.x;
    const int wv   = tid >> 6;
    const int lane = tid & 63;
    float* mysm = smem + wv * 576;             // wave-private region

    const int gbase = blockIdx.x << 8;         // block face base
    const int gw    = gbase + (wv << 6);       // wave face base
    const int g     = gw + lane;               // global face index

    // ---- front burst (all coalesced) ----
    const float4* sb  = s4 + ((size_t)gw * 9) / 4;   // gw*9 divisible by 4
    const float*  sbf = reinterpret_cast<const float*>(sb);
    float4 a0 = sb[lane];                      // source floats [0..255]
    float4 a1 = sb[lane + 64];                 // source floats [256..511]
    float  a2 = sbf[512 + lane];               // source floats [512..575]
    float4 kv = k4[g];

    const int bb = g / nfaces;                 // per-thread batch index
    const int f  = g - bb * nfaces;            // in-batch face index
    const int ow = own_f[f];                   // coalesced
    const int nw = nei_f[f];                   // coalesced

    // ---- stage into wave-private LDS ----
    float4* mysm4 = reinterpret_cast<float4*>(mysm);
    mysm4[lane]      = a0;
    mysm4[lane + 64] = a1;
    mysm[512 + lane] = a2;

    // ---- issue the one dependent gather early ----
    float o = 0.0f, n = 0.0f;
    const bool lim = (ow >= 0);
    if (lim) {
        const float* ucb = uc + (size_t)bb * ncells;
        o = ucb[ow];
        n = ucb[nw];
    }

    // ---- uniform weights -> SGPRs ----
    float Wr[4][9];
#pragma unroll
    for (int i = 0; i < 4; ++i)
#pragma unroll
        for (int s = 0; s < 9; ++s)
            Wr[i][s] = W[i * 9 + s];
    float br[9];
#pragma unroll
    for (int s = 0; s < 9; ++s) br[s] = bias[s];

    // ---- dot (gather latency hides under these 45 FMAs) ----
    const float* S = mysm + lane * 9;          // stride 9: gcd(9,32)=1, no conflicts
    float acc = 0.0f;
#pragma unroll
    for (int s = 0; s < 9; ++s) {
        float c = br[s];
        c = fmaf(kv.x, Wr[0][s], c);
        c = fmaf(kv.y, Wr[1][s], c);
        c = fmaf(kv.z, Wr[2][s], c);
        c = fmaf(kv.w, Wr[3][s], c);
        acc = fmaf(c, S[s], acc);
    }

    float res = acc;
    if (lim) {
        float smax = fmaxf(o, n);
        float smin = fminf(o, n);
        float flux = 0.5f * (o + n);
        float up   = (flux >= 0.0f) ? o : n;
        float hi   = smax + BOUNDING_PERC * fabsf(smax);
        float lo   = smin - BOUNDING_PERC * fabsf(smin);
        bool valid = (acc >= lo) && (acc <= hi);
        res = valid ? acc : up;
    }
    out[g] = res;
}

// ---------------------------------------------------------------------------
// Fallback pass-1/pass-2 (used only if ws_size is too small)
// ---------------------------------------------------------------------------
__global__ __launch_bounds__(256) void ufaces_kernel(
    const float4* __restrict__ k4, const float4* __restrict__ s4,
    const float* __restrict__ W, const float* __restrict__ bias,
    float* __restrict__ out)
{
    __shared__ float s_src[2304];
    const int tid = threadIdx.x;
    const int base_face = blockIdx.x << 8;
    {
        const float4* src_blk = s4 + ((size_t)base_face * 9) / 4;
        float4* sm4 = reinterpret_cast<float4*>(s_src);
        sm4[tid]       = src_blk[tid];
        sm4[tid + 256] = src_blk[tid + 256];
        if (tid < 64) sm4[tid + 512] = src_blk[tid + 512];
    }
    float Wr[4][9];
#pragma unroll
    for (int i = 0; i < 4; ++i)
#pragma unroll
        for (int s = 0; s < 9; ++s) Wr[i][s] = W[i * 9 + s];
    float br[9];
#pragma unroll
    for (int s = 0; s < 9; ++s) br[s] = bias[s];
    const float4 kv = k4[base_face + tid];
    __syncthreads();
    const float* S = &s_src[tid * 9];
    float acc = 0.0f;
#pragma unroll
    for (int s = 0; s < 9; ++s) {
        float c = br[s];
        c = fmaf(kv.x, Wr[0][s], c);
        c = fmaf(kv.y, Wr[1][s], c);
        c = fmaf(kv.z, Wr[2][s], c);
        c = fmaf(kv.w, Wr[3][s], c);
        acc = fmaf(c, S[s], acc);
    }
    out[base_face + tid] = acc;
}

__global__ __launch_bounds__(256) void bound_kernel(
    const float* __restrict__ uc, const int* __restrict__ pos,
    const int* __restrict__ own, const int* __restrict__ nei,
    float* __restrict__ out, int nb, int nfaces, int ncells, int nbatch)
{
    int idx = blockIdx.x * blockDim.x + threadIdx.x;
    if (idx >= nbatch * nb) return;
    int j  = idx % nb;
    int bb = idx / nb;
    int p = pos[j];
    float uf = out[bb * nfaces + p];
    float o  = uc[bb * ncells + own[j]];
    float n  = uc[bb * ncells + nei[j]];
    float smax = fmaxf(o, n);
    float smin = fminf(o, n);
    float flux = 0.5f * (o + n);
    float up   = (flux >= 0.0f) ? o : n;
    float hi   = smax + BOUNDING_PERC * fabsf(smax);
    float lo   = smin - BOUNDING_PERC * fabsf(smin);
    bool valid = (uf >= lo) && (uf <= hi);
    out[bb * nfaces + p] = valid ? uf : up;
}

extern "C" void kernel_launch(void* const* d_in, const int* in_sizes, int n_in,
                              void* d_out, int out_size, void* d_ws, size_t ws_size,
                              hipStream_t stream)
{
    const float* kernel_in  = (const float*)d_in[0];  // (b, nfaces, 4)
    const float* source     = (const float*)d_in[1];  // (b, nfaces, 3, 3)
    const float* ucenters   = (const float*)d_in[2];  // (b, ncells)
    const float* W          = (const float*)d_in[3];  // (4, 9)
    const float* bias       = (const float*)d_in[4];  // (9,)
    const int*   positions  = (const int*)d_in[5];    // (nb,)
    const int*   owners     = (const int*)d_in[6];    // (nb,)
    const int*   neighbours = (const int*)d_in[7];    // (nb,)
    float*       out        = (float*)d_out;          // (b, nfaces)

    const int b      = 4;
    const int in_dim = 4;
    const int nfaces = in_sizes[0] / (b * in_dim);
    const int ncells = in_sizes[2] / b;
    const int nb     = in_sizes[5];
    const int total_faces = b * nfaces;               // 4,000,000 (div by 256)

    if (ws_size >= 2 * (size_t)nfaces * sizeof(int)) {
        int* own_f = (int*)d_ws;
        int* nei_f = own_f + nfaces;
        // own_f[f] = -1 sentinel
        hipMemsetAsync(own_f, 0xFF, (size_t)nfaces * sizeof(int), stream);
        // scatter owners/neighbours to face slots
        scatter_on_kernel<<<(nb + 255) / 256, 256, 0, stream>>>(
            positions, owners, neighbours, own_f, nei_f, nb);
        // fused compute + bound + store (barrier-free)
        fused_kernel<<<total_faces / 256, 256, 0, stream>>>(
            (const float4*)kernel_in, (const float4*)source, W, bias,
            own_f, nei_f, ucenters, out, nfaces, ncells);
    } else {
        ufaces_kernel<<<total_faces / 256, 256, 0, stream>>>(
            (const float4*)kernel_in, (const float4*)source, W, bias, out);
        int total = b * nb;
        bound_kernel<<<(total + 255) / 256, 256, 0, stream>>>(
            ucenters, positions, owners, neighbours, out, nb, nfaces, ncells, b);
    }
}